// Round 2
// baseline (361.075 us; speedup 1.0000x reference)
//
#include <hip/hip_runtime.h>
#include <hip/hip_bf16.h>

#define BSZ 8
#define CDIM 512
#define KDIM 512
#define HWSZ 16384   // 128*128
#define NPIX (BSZ*HWSZ)  // 131072

using bf16x8 = __attribute__((ext_vector_type(8))) short;
using f32x4  = __attribute__((ext_vector_type(4))) float;

// ---------------- prep: Eb[k][c] = bf16( E[k][c] / ||E[k]|| ) ----------------
__global__ __launch_bounds__(64) void prep_emb_kernel(const float* __restrict__ E,
                                                      unsigned short* __restrict__ Eb) {
  int k = blockIdx.x;
  int lane = threadIdx.x;
  const float4* row = (const float4*)(E + (size_t)k * CDIM);
  float4 v0 = row[lane * 2], v1 = row[lane * 2 + 1];
  float ss = v0.x*v0.x + v0.y*v0.y + v0.z*v0.z + v0.w*v0.w
           + v1.x*v1.x + v1.y*v1.y + v1.z*v1.z + v1.w*v1.w;
  #pragma unroll
  for (int d = 1; d < 64; d <<= 1) ss += __shfl_xor(ss, d, 64);
  float rinv = rsqrtf(fmaxf(ss, 1e-24f));
  float f[8] = {v0.x, v0.y, v0.z, v0.w, v1.x, v1.y, v1.z, v1.w};
  unsigned o[8];
  #pragma unroll
  for (int e = 0; e < 8; ++e) {
    float x = f[e] * rinv;
    unsigned u = __builtin_bit_cast(unsigned, x);
    o[e] = (u + 0x7FFFu + ((u >> 16) & 1u)) >> 16;   // RNE f32->bf16
  }
  uint4 pack;
  pack.x = o[0] | (o[1] << 16);
  pack.y = o[2] | (o[3] << 16);
  pack.z = o[4] | (o[5] << 16);
  pack.w = o[6] | (o[7] << 16);
  ((uint4*)(Eb + (size_t)k * CDIM))[lane] = pack;
}

// ---------------- gt_count[k] = sum over (b,h,w) of ann[b,k,h,w] ----------------
__global__ __launch_bounds__(256) void gt_count_kernel(const float* __restrict__ ANN,
                                                       float* __restrict__ gt_count) {
  int slice = blockIdx.x;            // b*KDIM + k
  int k = slice & (KDIM - 1);
  const float4* p = (const float4*)(ANN + (size_t)slice * HWSZ);
  float s = 0.f;
  #pragma unroll
  for (int i = 0; i < 16; ++i) {
    float4 v = p[threadIdx.x + i * 256];
    s += v.x + v.y + v.z + v.w;
  }
  #pragma unroll
  for (int d = 1; d < 64; d <<= 1) s += __shfl_xor(s, d, 64);
  __shared__ float sw[4];
  if ((threadIdx.x & 63) == 0) sw[threadIdx.x >> 6] = s;
  __syncthreads();
  if (threadIdx.x == 0) {
    atomicAdd(&gt_count[k], sw[0] + sw[1] + sw[2] + sw[3]);
  }
}

// ---------------- pass A: Xt[pix][c] = bf16(X[b][c][hw])  (LDS transpose) ----------------
// tile: 64 px  x 32 c per block. LDS rows = 64 px, row stride 68 B (17 u32) ->
// writes 2-way bank aliasing (free), reads 2-way, global in/out coalesced.
__global__ __launch_bounds__(256) void transpose_kernel(const float* __restrict__ X,
                                                        unsigned short* __restrict__ Xt) {
  __shared__ unsigned int lds[64 * 17];
  int t  = threadIdx.x;
  int pb = blockIdx.x & 2047, cb = blockIdx.x >> 11;
  int px0 = pb * 64, c0 = cb * 32;
  int b   = px0 >> 14, hw = px0 & (HWSZ - 1);
  int p   = t & 15, cp = t >> 4;                       // px-quad, c-pair
  const float* src = X + ((size_t)b * CDIM + c0 + 2 * cp) * HWSZ + hw + 4 * p;
  float4 v0 = *(const float4*)src;                     // c
  float4 v1 = *(const float4*)(src + HWSZ);            // c+1
  float f0[4] = {v0.x, v0.y, v0.z, v0.w};
  float f1[4] = {v1.x, v1.y, v1.z, v1.w};
  #pragma unroll
  for (int j = 0; j < 4; ++j) {
    unsigned u = (__builtin_bit_cast(unsigned, f0[j]) >> 16)
               | (__builtin_bit_cast(unsigned, f1[j]) & 0xFFFF0000u);   // [c | c+1] bf16 pair
    lds[(4 * p + j) * 17 + cp] = u;                    // row = px-local, col = c-pair
  }
  __syncthreads();
  int px_l = t >> 2, ch = t & 3;                       // 4 chunks of 8c (16B) per row
  unsigned r0 = lds[px_l * 17 + ch * 4 + 0];
  unsigned r1 = lds[px_l * 17 + ch * 4 + 1];
  unsigned r2 = lds[px_l * 17 + ch * 4 + 2];
  unsigned r3 = lds[px_l * 17 + ch * 4 + 3];
  uint4 o; o.x = r0; o.y = r1; o.z = r2; o.w = r3;
  *(uint4*)(Xt + (size_t)(px0 + px_l) * CDIM + c0 + ch * 8) = o;
}

// ---------------- pass B: GEMM(Xt, Eb^T) + argmax + count update ----------------
// 512 threads = 8 waves = 2 px-halves x 4 k-groups; block = 128 px x 512 k.
// A-frags: direct b128 from Xt (L3-hot).  B-frags: direct b128 from Eb (L2).
__global__ __launch_bounds__(512, 2) void gemm_argmax2(
    const unsigned short* __restrict__ Xt, const float* __restrict__ ANN,
    const unsigned short* __restrict__ Eb,
    int* __restrict__ pred_count, int* __restrict__ inter) {
  int tid  = threadIdx.x;
  int wv   = tid >> 6;
  int kw   = wv & 3;            // k-group: 128 k each
  int mw   = wv >> 2;           // px-half: 64 px each
  int lane = tid & 63;
  int p15  = lane & 15, q = lane >> 4;
  int px0  = blockIdx.x * 128;
  int b    = px0 >> 14;
  int hw   = px0 & (HWSZ - 1);

  const unsigned short* Xr = Xt + (size_t)(px0 + mw * 64 + p15) * CDIM + q * 8;
  const unsigned short* Er = Eb + (size_t)(kw * 128 + p15) * CDIM + q * 8;

  f32x4 acc[4][8];
  #pragma unroll
  for (int m = 0; m < 4; ++m)
    #pragma unroll
    for (int n = 0; n < 8; ++n)
      acc[m][n] = (f32x4){0.f, 0.f, 0.f, 0.f};

  for (int cs = 0; cs < 16; ++cs) {
    bf16x8 a[4];
    #pragma unroll
    for (int m = 0; m < 4; ++m)
      a[m] = *(const bf16x8*)(Xr + (size_t)m * 16 * CDIM + cs * 32);
    bf16x8 bb[8];
    #pragma unroll
    for (int n = 0; n < 8; ++n)
      bb[n] = *(const bf16x8*)(Er + (size_t)n * 16 * CDIM + cs * 32);
    #pragma unroll
    for (int n = 0; n < 8; ++n)
      #pragma unroll
      for (int m = 0; m < 4; ++m)
        acc[m][n] = __builtin_amdgcn_mfma_f32_16x16x32_bf16(a[m], bb[n], acc[m][n], 0, 0, 0);
  }

  // D layout: col(k) = lane&15, row(px) = (lane>>4)*4 + reg  [m89-verified]
  __shared__ float s_v[4][128];
  __shared__ int   s_k[4][128];
  #pragma unroll
  for (int m = 0; m < 4; ++m) {
    #pragma unroll
    for (int r = 0; r < 4; ++r) {
      float best = acc[m][0][r];
      int bn = 0;
      #pragma unroll
      for (int n = 1; n < 8; ++n) {
        float v = acc[m][n][r];
        if (v > best) { best = v; bn = n; }
      }
      int bk = kw * 128 + bn * 16 + p15;
      #pragma unroll
      for (int d = 1; d < 16; d <<= 1) {   // butterfly over 16 k-col lanes
        float ov = __shfl_xor(best, d, 64);
        int   ok = __shfl_xor(bk, d, 64);
        if (ov > best || (ov == best && ok < bk)) { best = ov; bk = ok; }
      }
      if (p15 == 0) {
        int p = mw * 64 + m * 16 + q * 4 + r;   // pixel within block
        s_v[kw][p] = best;
        s_k[kw][p] = bk;
      }
    }
  }
  __syncthreads();
  if (tid < 128) {
    int p = tid;
    float best = s_v[0][p]; int bk = s_k[0][p];
    #pragma unroll
    for (int w = 1; w < 4; ++w) {
      float v = s_v[w][p]; int kk = s_k[w][p];
      if (v > best || (v == best && kk < bk)) { best = v; bk = kk; }
    }
    atomicAdd(&pred_count[bk], 1);
    float g = ANN[((size_t)b * KDIM + bk) * HWSZ + hw + p];   // one-hot gather
    if (g > 0.5f) atomicAdd(&inter[bk], 1);
  }
}

// ---------------- fallback one-pass kernel (used only if ws too small) ----------------
__global__ __launch_bounds__(256, 1) void gemm_argmax_kernel(
    const float* __restrict__ X, const float* __restrict__ ANN,
    const unsigned short* __restrict__ Eb,
    int* __restrict__ pred_count, int* __restrict__ inter) {
  int tid  = threadIdx.x;
  int wv   = tid >> 6;
  int lane = tid & 63;
  int p15  = lane & 15, q = lane >> 4;
  int pix0 = blockIdx.x * 64;
  int b    = pix0 >> 14;
  int hw   = pix0 & (HWSZ - 1);
  const float*          Xb = X  + (size_t)b * CDIM * HWSZ + hw + p15;
  const unsigned short* Ew = Eb + (size_t)(wv * 128) * CDIM;
  f32x4 acc[4][8];
  #pragma unroll
  for (int m = 0; m < 4; ++m)
    #pragma unroll
    for (int n = 0; n < 8; ++n)
      acc[m][n] = (f32x4){0.f, 0.f, 0.f, 0.f};
  for (int cs = 0; cs < 16; ++cs) {
    int c0 = cs * 32 + q * 8;
    bf16x8 a[4];
    #pragma unroll
    for (int m = 0; m < 4; ++m)
      #pragma unroll
      for (int e = 0; e < 8; ++e) {
        float x = Xb[(size_t)(c0 + e) * HWSZ + m * 16];
        a[m][e] = (short)(__builtin_bit_cast(unsigned, x) >> 16);
      }
    bf16x8 bfrag[8];
    #pragma unroll
    for (int n = 0; n < 8; ++n)
      bfrag[n] = *(const bf16x8*)(Ew + (size_t)(n * 16 + p15) * CDIM + cs * 32 + q * 8);
    #pragma unroll
    for (int n = 0; n < 8; ++n)
      #pragma unroll
      for (int m = 0; m < 4; ++m)
        acc[m][n] = __builtin_amdgcn_mfma_f32_16x16x32_bf16(a[m], bfrag[n], acc[m][n], 0, 0, 0);
  }
  __shared__ float s_v[4][64];
  __shared__ int   s_k[4][64];
  #pragma unroll
  for (int m = 0; m < 4; ++m)
    #pragma unroll
    for (int r = 0; r < 4; ++r) {
      float best = acc[m][0][r];
      int bn = 0;
      #pragma unroll
      for (int n = 1; n < 8; ++n) {
        float v = acc[m][n][r];
        if (v > best) { best = v; bn = n; }
      }
      int bk = wv * 128 + bn * 16 + p15;
      #pragma unroll
      for (int d = 1; d < 16; d <<= 1) {
        float ov = __shfl_xor(best, d, 64);
        int   ok = __shfl_xor(bk, d, 64);
        if (ov > best || (ov == best && ok < bk)) { best = ov; bk = ok; }
      }
      if (p15 == 0) {
        int p = m * 16 + q * 4 + r;
        s_v[wv][p] = best;
        s_k[wv][p] = bk;
      }
    }
  __syncthreads();
  if (tid < 64) {
    int p = tid;
    float best = s_v[0][p]; int bk = s_k[0][p];
    #pragma unroll
    for (int w = 1; w < 4; ++w) {
      float v = s_v[w][p]; int kk = s_k[w][p];
      if (v > best || (v == best && kk < bk)) { best = v; bk = kk; }
    }
    atomicAdd(&pred_count[bk], 1);
    float g = ANN[((size_t)b * KDIM + bk) * HWSZ + hw + p];
    if (g > 0.5f) atomicAdd(&inter[bk], 1);
  }
}

// ---------------- final dice reduction ----------------
__global__ __launch_bounds__(512) void final_kernel(
    const int* __restrict__ pred_count, const int* __restrict__ inter,
    const float* __restrict__ gt_count, float* __restrict__ out) {
  int k = threadIdx.x;
  float G = gt_count[k];
  float P = (float)pred_count[k];
  float I = (float)inter[k];
  float card  = P + G;
  float score = (2.f * I + 1e-4f) / fmaxf(card + 1e-4f, 1e-7f);
  float v = (G > 0.f) ? (1.f - score) : 0.f;
  #pragma unroll
  for (int d = 1; d < 64; d <<= 1) v += __shfl_xor(v, d, 64);
  __shared__ float sw[8];
  if ((k & 63) == 0) sw[k >> 6] = v;
  __syncthreads();
  if (k == 0) {
    float s = 0.f;
    #pragma unroll
    for (int i = 0; i < 8; ++i) s += sw[i];
    out[0] = s / (float)KDIM;
  }
}

extern "C" void kernel_launch(void* const* d_in, const int* in_sizes, int n_in,
                              void* d_out, int out_size, void* d_ws, size_t ws_size,
                              hipStream_t stream) {
  const float* X   = (const float*)d_in[0];   // [8,512,128,128] fp32
  const float* ANN = (const float*)d_in[1];   // [8,512,128,128] fp32 one-hot
  const float* E   = (const float*)d_in[2];   // [512,512] fp32

  char* base = (char*)d_ws;
  unsigned short* Eb = (unsigned short*)base;                 // 512 KiB
  float* gt_count    = (float*)(base + 524288);
  int*   pred_count  = (int*)  (base + 524288 + 2048);
  int*   inter       = (int*)  (base + 524288 + 4096);
  unsigned short* Xt = (unsigned short*)(base + (1u << 20));  // 128 MiB [pix][c] bf16

  size_t need = (size_t)(1u << 20) + (size_t)NPIX * CDIM * 2;

  hipMemsetAsync(base + 524288, 0, 6144, stream);
  prep_emb_kernel<<<KDIM, 64, 0, stream>>>(E, Eb);
  gt_count_kernel<<<BSZ * KDIM, 256, 0, stream>>>(ANN, gt_count);   // before transpose: keep Xt L3-hot
  if (ws_size >= need) {
    transpose_kernel<<<2048 * 16, 256, 0, stream>>>(X, Xt);
    gemm_argmax2<<<NPIX / 128, 512, 0, stream>>>(Xt, ANN, Eb, pred_count, inter);
  } else {
    gemm_argmax_kernel<<<NPIX / 64, 256, 0, stream>>>(X, ANN, Eb, pred_count, inter);
  }
  final_kernel<<<1, 512, 0, stream>>>(pred_count, inter, gt_count, (float*)d_out);
}

// Round 3
// 241.777 us; speedup vs baseline: 1.4934x; 1.4934x over previous
//
#include <hip/hip_runtime.h>
#include <hip/hip_bf16.h>

#define BSZ 8
#define CDIM 512
#define KDIM 512
#define HWSZ 16384   // 128*128
#define NPIX (BSZ*HWSZ)  // 131072

#define ROWU 20      // LDS row stride in u32 (80 B): 16B-aligned, conflict-free r/w

using bf16x8 = __attribute__((ext_vector_type(8))) short;
using f32x4  = __attribute__((ext_vector_type(4))) float;

// ---------------- prep: Eb[k][c] = bf16( E[k][c] / ||E[k]|| ) ----------------
__global__ __launch_bounds__(64) void prep_emb_kernel(const float* __restrict__ E,
                                                      unsigned short* __restrict__ Eb) {
  int k = blockIdx.x;
  int lane = threadIdx.x;
  const float4* row = (const float4*)(E + (size_t)k * CDIM);
  float4 v0 = row[lane * 2], v1 = row[lane * 2 + 1];
  float ss = v0.x*v0.x + v0.y*v0.y + v0.z*v0.z + v0.w*v0.w
           + v1.x*v1.x + v1.y*v1.y + v1.z*v1.z + v1.w*v1.w;
  #pragma unroll
  for (int d = 1; d < 64; d <<= 1) ss += __shfl_xor(ss, d, 64);
  float rinv = rsqrtf(fmaxf(ss, 1e-24f));
  float f[8] = {v0.x, v0.y, v0.z, v0.w, v1.x, v1.y, v1.z, v1.w};
  unsigned o[8];
  #pragma unroll
  for (int e = 0; e < 8; ++e) {
    float x = f[e] * rinv;
    unsigned u = __builtin_bit_cast(unsigned, x);
    o[e] = (u + 0x7FFFu + ((u >> 16) & 1u)) >> 16;   // RNE f32->bf16
  }
  uint4 pack;
  pack.x = o[0] | (o[1] << 16);
  pack.y = o[2] | (o[3] << 16);
  pack.z = o[4] | (o[5] << 16);
  pack.w = o[6] | (o[7] << 16);
  ((uint4*)(Eb + (size_t)k * CDIM))[lane] = pack;
}

// ---------------- gt_count[k] = sum over (b,h,w) of ann[b,k,h,w] ----------------
__global__ __launch_bounds__(256) void gt_count_kernel(const float* __restrict__ ANN,
                                                       float* __restrict__ gt_count) {
  int slice = blockIdx.x;            // b*KDIM + k
  int k = slice & (KDIM - 1);
  const float4* p = (const float4*)(ANN + (size_t)slice * HWSZ);
  float s = 0.f;
  #pragma unroll
  for (int i = 0; i < 16; ++i) {
    float4 v = p[threadIdx.x + i * 256];
    s += v.x + v.y + v.z + v.w;
  }
  #pragma unroll
  for (int d = 1; d < 64; d <<= 1) s += __shfl_xor(s, d, 64);
  __shared__ float sw[4];
  if ((threadIdx.x & 63) == 0) sw[threadIdx.x >> 6] = s;
  __syncthreads();
  if (threadIdx.x == 0) {
    atomicAdd(&gt_count[k], sw[0] + sw[1] + sw[2] + sw[3]);
  }
}

// ---------------- fused: X -> (LDS transpose+bf16) -> GEMM -> argmax -> counts ----------------
// block = 256 threads = 4 waves; wave wv owns k-cols [wv*128, wv*128+128).
// block owns 64 px. K(=C) processed in 16 slices of 32 c, double-buffered LDS.
__global__ __launch_bounds__(256, 2) void gemm_fused(
    const float* __restrict__ X, const float* __restrict__ ANN,
    const unsigned short* __restrict__ Eb,
    int* __restrict__ pred_count, int* __restrict__ inter) {
  __shared__ unsigned int lds[2][64 * ROWU];
  int tid  = threadIdx.x;
  int wv   = tid >> 6;          // k-group 0..3
  int lane = tid & 63;
  int p15  = lane & 15, q = lane >> 4;
  int cp   = tid & 15;          // c-pair 0..15 (c fastest -> conflict-free LDS writes)
  int pq   = tid >> 4;          // px-quad 0..15
  int px0  = blockIdx.x * 64;
  int b    = px0 >> 14;
  int hw   = px0 & (HWSZ - 1);

  const float*          Xs = X  + ((size_t)b * CDIM + 2 * cp) * HWSZ + hw + 4 * pq;
  const unsigned short* Er = Eb + (size_t)(wv * 128 + p15) * CDIM + q * 8;

  // ---- stage slice 0 into lds[0] ----
  {
    float4 v0 = *(const float4*)Xs;
    float4 v1 = *(const float4*)(Xs + HWSZ);
    float f0[4] = {v0.x, v0.y, v0.z, v0.w};
    float f1[4] = {v1.x, v1.y, v1.z, v1.w};
    #pragma unroll
    for (int j = 0; j < 4; ++j) {
      unsigned u = (__builtin_bit_cast(unsigned, f0[j]) >> 16)
                 | (__builtin_bit_cast(unsigned, f1[j]) & 0xFFFF0000u);
      lds[0][(4 * pq + j) * ROWU + cp] = u;   // row = px-local, col = c-pair
    }
  }

  f32x4 acc[4][8];
  #pragma unroll
  for (int m = 0; m < 4; ++m)
    #pragma unroll
    for (int n = 0; n < 8; ++n)
      acc[m][n] = (f32x4){0.f, 0.f, 0.f, 0.f};

  for (int cs = 0; cs < 16; ++cs) {
    int cur = cs & 1;
    // B frags for this slice (global, L2-resident) — issue before barrier
    bf16x8 bb[8];
    #pragma unroll
    for (int n = 0; n < 8; ++n)
      bb[n] = *(const bf16x8*)(Er + (size_t)n * 16 * CDIM + cs * 32);
    // prefetch next X slice into regs (2-phase: hide HBM under MFMA)
    float4 w0, w1;
    if (cs < 15) {
      const float* nsrc = Xs + (size_t)(cs + 1) * 32 * HWSZ;
      w0 = *(const float4*)nsrc;
      w1 = *(const float4*)(nsrc + HWSZ);
    }
    __syncthreads();                       // lds[cur] ready for all waves
    bf16x8 a[4];
    #pragma unroll
    for (int m = 0; m < 4; ++m)
      a[m] = *(bf16x8*)&lds[cur][(m * 16 + p15) * ROWU + q * 4];  // ds_read_b128
    #pragma unroll
    for (int n = 0; n < 8; ++n)
      #pragma unroll
      for (int m = 0; m < 4; ++m)
        acc[m][n] = __builtin_amdgcn_mfma_f32_16x16x32_bf16(a[m], bb[n], acc[m][n], 0, 0, 0);
    // write next slice into the other buffer (readers of it sync at next top-barrier)
    if (cs < 15) {
      float f0[4] = {w0.x, w0.y, w0.z, w0.w};
      float f1[4] = {w1.x, w1.y, w1.z, w1.w};
      #pragma unroll
      for (int j = 0; j < 4; ++j) {
        unsigned u = (__builtin_bit_cast(unsigned, f0[j]) >> 16)
                   | (__builtin_bit_cast(unsigned, f1[j]) & 0xFFFF0000u);
        lds[cur ^ 1][(4 * pq + j) * ROWU + cp] = u;
      }
    }
  }

  // ---- argmax epilogue: D layout col(k)=lane&15, row(px)=(lane>>4)*4+reg ----
  __shared__ float s_v[4][64];
  __shared__ int   s_k[4][64];
  #pragma unroll
  for (int m = 0; m < 4; ++m) {
    #pragma unroll
    for (int r = 0; r < 4; ++r) {
      float best = acc[m][0][r];
      int bn = 0;
      #pragma unroll
      for (int n = 1; n < 8; ++n) {
        float v = acc[m][n][r];
        if (v > best) { best = v; bn = n; }
      }
      int bk = wv * 128 + bn * 16 + p15;
      #pragma unroll
      for (int d = 1; d < 16; d <<= 1) {   // butterfly over 16 k-col lanes
        float ov = __shfl_xor(best, d, 64);
        int   ok = __shfl_xor(bk, d, 64);
        if (ov > best || (ov == best && ok < bk)) { best = ov; bk = ok; }
      }
      if (p15 == 0) {
        int p = m * 16 + q * 4 + r;        // pixel within block
        s_v[wv][p] = best;
        s_k[wv][p] = bk;
      }
    }
  }
  __syncthreads();
  if (tid < 64) {
    int p = tid;
    float best = s_v[0][p]; int bk = s_k[0][p];
    #pragma unroll
    for (int w = 1; w < 4; ++w) {
      float v = s_v[w][p]; int kk = s_k[w][p];
      if (v > best || (v == best && kk < bk)) { best = v; bk = kk; }
    }
    atomicAdd(&pred_count[bk], 1);
    float g = ANN[((size_t)b * KDIM + bk) * HWSZ + hw + p];   // one-hot gather
    if (g > 0.5f) atomicAdd(&inter[bk], 1);
  }
}

// ---------------- final dice reduction ----------------
__global__ __launch_bounds__(512) void final_kernel(
    const int* __restrict__ pred_count, const int* __restrict__ inter,
    const float* __restrict__ gt_count, float* __restrict__ out) {
  int k = threadIdx.x;
  float G = gt_count[k];
  float P = (float)pred_count[k];
  float I = (float)inter[k];
  float card  = P + G;
  float score = (2.f * I + 1e-4f) / fmaxf(card + 1e-4f, 1e-7f);
  float v = (G > 0.f) ? (1.f - score) : 0.f;
  #pragma unroll
  for (int d = 1; d < 64; d <<= 1) v += __shfl_xor(v, d, 64);
  __shared__ float sw[8];
  if ((k & 63) == 0) sw[k >> 6] = v;
  __syncthreads();
  if (k == 0) {
    float s = 0.f;
    #pragma unroll
    for (int i = 0; i < 8; ++i) s += sw[i];
    out[0] = s / (float)KDIM;
  }
}

extern "C" void kernel_launch(void* const* d_in, const int* in_sizes, int n_in,
                              void* d_out, int out_size, void* d_ws, size_t ws_size,
                              hipStream_t stream) {
  const float* X   = (const float*)d_in[0];   // [8,512,128,128] fp32
  const float* ANN = (const float*)d_in[1];   // [8,512,128,128] fp32 one-hot
  const float* E   = (const float*)d_in[2];   // [512,512] fp32

  char* base = (char*)d_ws;
  unsigned short* Eb = (unsigned short*)base;                 // 512 KiB
  float* gt_count    = (float*)(base + 524288);
  int*   pred_count  = (int*)  (base + 524288 + 2048);
  int*   inter       = (int*)  (base + 524288 + 4096);

  hipMemsetAsync(base + 524288, 0, 6144, stream);
  prep_emb_kernel<<<KDIM, 64, 0, stream>>>(E, Eb);
  gt_count_kernel<<<BSZ * KDIM, 256, 0, stream>>>(ANN, gt_count);
  gemm_fused<<<NPIX / 64, 256, 0, stream>>>(X, ANN, Eb, pred_count, inter);
  final_kernel<<<1, 512, 0, stream>>>(pred_count, inter, gt_count, (float*)d_out);
}